// Round 3
// baseline (481.862 us; speedup 1.0000x reference)
//
#include <hip/hip_runtime.h>
#include <stdint.h>

#define N_PTS 1000000
#define B_SEG 64
#define HID 128
#define AFFD 16
#define AH 64
#define AL 32
#define AA 8

// Output flat offsets in FLOAT elements (return order: affordances, recon_pos,
// coh_signal, coh_spatial, agent_action, agent_h_next). Output dtype: float32.
#define O_AFF 0
#define O_REC (16 * N_PTS)
#define O_SIG (19 * N_PTS)
#define O_SPA (19 * N_PTS + B_SEG)
#define O_ACT (20 * N_PTS + B_SEG)
#define O_HN  (20 * N_PTS + B_SEG + B_SEG * AA)

// ---------------------------------------------------------------------------
// Kernel 1: per-point MLPs (F then G), per-point outputs, segment-sum into ws.
// ws layout: [seg][18] = {err_sum, count, aff_sum[16]}   (fp32)
// Inputs: float32. Outputs: float32.
// ---------------------------------------------------------------------------
__global__ __launch_bounds__(256) void point_kernel(
    const float* __restrict__ pos, const int* __restrict__ batch,
    const float* __restrict__ Wf1, const float* __restrict__ bf1v,
    const float* __restrict__ Wf2, const float* __restrict__ bf2v,
    const float* __restrict__ Wg1, const float* __restrict__ bg1v,
    const float* __restrict__ Wg2, const float* __restrict__ bg2v,
    float* __restrict__ out, float* __restrict__ ws) {
  // LDS-staged weights, packed for float4 broadcast reads (wave-uniform ->
  // conflict-free broadcasts).
  __shared__ float sF1[HID * 4];    // j*4: Wf1[0][j], Wf1[1][j], Wf1[2][j], bf1[j]
  __shared__ float sF2[HID * AFFD]; // j*16+k : Wf2[j][k]
  __shared__ float sG1[HID * AFFD]; // j*16+k : Wg1[k][j]  (transposed)
  __shared__ float sG2[HID * 4];    // j*4: Wg2[j][0..2], bg1[j]
  __shared__ float sBf2[AFFD];

  const int tid = threadIdx.x;
  for (int j = tid; j < HID; j += 256) {
    sF1[j * 4 + 0] = Wf1[0 * HID + j];
    sF1[j * 4 + 1] = Wf1[1 * HID + j];
    sF1[j * 4 + 2] = Wf1[2 * HID + j];
    sF1[j * 4 + 3] = bf1v[j];
    sG2[j * 4 + 0] = Wg2[j * 3 + 0];
    sG2[j * 4 + 1] = Wg2[j * 3 + 1];
    sG2[j * 4 + 2] = Wg2[j * 3 + 2];
    sG2[j * 4 + 3] = bg1v[j];
  }
  for (int i = tid; i < HID * AFFD; i += 256) {
    sF2[i] = Wf2[i];
    int j = i >> 4, k = i & 15;
    sG1[i] = Wg1[k * HID + j];
  }
  if (tid < AFFD) sBf2[tid] = bf2v[tid];
  const float bg20 = bg2v[0], bg21 = bg2v[1], bg22 = bg2v[2];
  __syncthreads();

  const float4* sF1v = (const float4*)sF1;
  const float4* sG2v = (const float4*)sG2;
  const int stride = gridDim.x * 256;

  // base is block-uniform -> whole wave stays together (shuffles below).
  for (int base = blockIdx.x * 256; base < N_PTS; base += stride) {
    const int p = base + tid;
    const bool valid = (p < N_PTS);
    int seg = -1;
    float err = 0.f;
    float aff[AFFD];
#pragma unroll
    for (int k = 0; k < AFFD; k++) aff[k] = 0.f;

    if (valid) {
      const float px = pos[p * 3 + 0];
      const float py = pos[p * 3 + 1];
      const float pz = pos[p * 3 + 2];
      seg = batch[p];
#pragma unroll
      for (int k = 0; k < AFFD; k++) aff[k] = sBf2[k];

      // F: 3 -> 128 (relu) -> 16, streamed over hidden j
#pragma unroll 4
      for (int j = 0; j < HID; j++) {
        float4 w = sF1v[j];
        float h = fmaf(px, w.x, fmaf(py, w.y, fmaf(pz, w.z, w.w)));
        h = fmaxf(h, 0.f);
        const float4* row = (const float4*)(sF2 + j * AFFD);
        float4 r0 = row[0], r1 = row[1], r2 = row[2], r3 = row[3];
        aff[0]  = fmaf(h, r0.x, aff[0]);  aff[1]  = fmaf(h, r0.y, aff[1]);
        aff[2]  = fmaf(h, r0.z, aff[2]);  aff[3]  = fmaf(h, r0.w, aff[3]);
        aff[4]  = fmaf(h, r1.x, aff[4]);  aff[5]  = fmaf(h, r1.y, aff[5]);
        aff[6]  = fmaf(h, r1.z, aff[6]);  aff[7]  = fmaf(h, r1.w, aff[7]);
        aff[8]  = fmaf(h, r2.x, aff[8]);  aff[9]  = fmaf(h, r2.y, aff[9]);
        aff[10] = fmaf(h, r2.z, aff[10]); aff[11] = fmaf(h, r2.w, aff[11]);
        aff[12] = fmaf(h, r3.x, aff[12]); aff[13] = fmaf(h, r3.y, aff[13]);
        aff[14] = fmaf(h, r3.z, aff[14]); aff[15] = fmaf(h, r3.w, aff[15]);
      }

      // G: 16 -> 128 (relu) -> 3, streamed over hidden j
      float rc0 = bg20, rc1 = bg21, rc2 = bg22;
#pragma unroll 4
      for (int j = 0; j < HID; j++) {
        float4 g = sG2v[j];
        const float4* row = (const float4*)(sG1 + j * AFFD);
        float4 r0 = row[0], r1 = row[1], r2 = row[2], r3 = row[3];
        float h = g.w;
        h = fmaf(aff[0], r0.x, h);  h = fmaf(aff[1], r0.y, h);
        h = fmaf(aff[2], r0.z, h);  h = fmaf(aff[3], r0.w, h);
        h = fmaf(aff[4], r1.x, h);  h = fmaf(aff[5], r1.y, h);
        h = fmaf(aff[6], r1.z, h);  h = fmaf(aff[7], r1.w, h);
        h = fmaf(aff[8], r2.x, h);  h = fmaf(aff[9], r2.y, h);
        h = fmaf(aff[10], r2.z, h); h = fmaf(aff[11], r2.w, h);
        h = fmaf(aff[12], r3.x, h); h = fmaf(aff[13], r3.y, h);
        h = fmaf(aff[14], r3.z, h); h = fmaf(aff[15], r3.w, h);
        h = fmaxf(h, 0.f);
        rc0 = fmaf(h, g.x, rc0);
        rc1 = fmaf(h, g.y, rc1);
        rc2 = fmaf(h, g.z, rc2);
      }

      const float dx = px - rc0, dy = py - rc1, dz = pz - rc2;
      err = fmaf(dx, dx, fmaf(dy, dy, dz * dz));

      // --- stores (fp32 outputs) ---
      float4* oa = (float4*)(out + O_AFF + (size_t)p * 16);  // 64B-aligned
      oa[0] = make_float4(aff[0], aff[1], aff[2], aff[3]);
      oa[1] = make_float4(aff[4], aff[5], aff[6], aff[7]);
      oa[2] = make_float4(aff[8], aff[9], aff[10], aff[11]);
      oa[3] = make_float4(aff[12], aff[13], aff[14], aff[15]);
      float* orc = out + O_REC + (size_t)p * 3;
      orc[0] = rc0;
      orc[1] = rc1;
      orc[2] = rc2;
      out[O_SPA + p] = err;
    }

    // --- segment reduction: 18 values {err, 1, aff[16]} ---
    float v[18];
    v[0] = err;
    v[1] = valid ? 1.f : 0.f;
#pragma unroll
    for (int k = 0; k < AFFD; k++) v[2 + k] = valid ? aff[k] : 0.f;

    const int first = __shfl(seg, 0);
    const bool uni = __all(seg == first);
    if (uni) {
#pragma unroll
      for (int i = 0; i < 18; i++) {
        float x = v[i];
        x += __shfl_down(x, 32);
        x += __shfl_down(x, 16);
        x += __shfl_down(x, 8);
        x += __shfl_down(x, 4);
        x += __shfl_down(x, 2);
        x += __shfl_down(x, 1);
        v[i] = x;
      }
      if ((tid & 63) == 0 && first >= 0) {
#pragma unroll
        for (int i = 0; i < 18; i++) atomicAdd(&ws[first * 18 + i], v[i]);
      }
    } else if (seg >= 0) {
#pragma unroll
      for (int i = 0; i < 18; i++) atomicAdd(&ws[seg * 18 + i], v[i]);
    }
  }
}

// ---------------------------------------------------------------------------
// Kernel 2: segment means -> coherence_signal, GRU cell, latent/action heads.
// Single block of 256 threads (B=64 is tiny). Inputs fp32, outputs fp32.
// ---------------------------------------------------------------------------
__global__ __launch_bounds__(256) void agent_kernel(
    const float* __restrict__ ws, const float* __restrict__ agent_h,
    const float* __restrict__ Wx, const float* __restrict__ Wh,
    const float* __restrict__ bx, const float* __restrict__ bh,
    const float* __restrict__ Wlat, const float* __restrict__ blat,
    const float* __restrict__ Wact, const float* __restrict__ bact,
    float* __restrict__ out) {
  __shared__ float sAff[B_SEG * AFFD];
  __shared__ float sH[B_SEG * AH];
  __shared__ float sHn[B_SEG * AH];
  __shared__ float sLat[B_SEG * AL];
  const int tid = threadIdx.x;

  for (int b = tid; b < B_SEG; b += 256) {
    float cnt = fmaxf(ws[b * 18 + 1], 1.f);
    out[O_SIG + b] = ws[b * 18 + 0] / cnt;
  }
  for (int i = tid; i < B_SEG * AFFD; i += 256) {
    int b = i >> 4, k = i & 15;
    float cnt = fmaxf(ws[b * 18 + 1], 1.f);
    sAff[i] = ws[b * 18 + 2 + k] / cnt;
  }
  for (int i = tid; i < B_SEG * AH; i += 256) sH[i] = agent_h[i];
  __syncthreads();

  // GRU: one thread per (b, jj) output element.
  for (int i = tid; i < B_SEG * AH; i += 256) {
    const int b = i >> 6, jj = i & 63;
    const float* ab = sAff + b * AFFD;
    const float* hb = sH + b * AH;
    float pr  = bx[jj] + bh[jj];
    float pz  = bx[64 + jj] + bh[64 + jj];
    float pnx = bx[128 + jj];
    float pnh = bh[128 + jj];
#pragma unroll
    for (int k = 0; k < AFFD; k++) {
      float a = ab[k];
      pr  = fmaf(a, Wx[k * 192 + jj], pr);
      pz  = fmaf(a, Wx[k * 192 + 64 + jj], pz);
      pnx = fmaf(a, Wx[k * 192 + 128 + jj], pnx);
    }
#pragma unroll
    for (int k = 0; k < AH; k++) {
      float h = hb[k];
      pr  = fmaf(h, Wh[k * 192 + jj], pr);
      pz  = fmaf(h, Wh[k * 192 + 64 + jj], pz);
      pnh = fmaf(h, Wh[k * 192 + 128 + jj], pnh);
    }
    float r = 1.f / (1.f + expf(-pr));
    float z = 1.f / (1.f + expf(-pz));
    float n = tanhf(pnx + r * pnh);
    float hn = (1.f - z) * n + z * hb[jj];
    sHn[i] = hn;
    out[O_HN + i] = hn;
  }
  __syncthreads();

  for (int i = tid; i < B_SEG * AL; i += 256) {
    const int b = i >> 5, l = i & 31;
    const float* hb = sHn + b * AH;
    float acc = blat[l];
#pragma unroll
    for (int k = 0; k < AH; k++) acc = fmaf(hb[k], Wlat[k * AL + l], acc);
    sLat[i] = tanhf(acc);
  }
  __syncthreads();

  for (int i = tid; i < B_SEG * AA; i += 256) {
    const int b = i >> 3, a = i & 7;
    const float* lb = sLat + b * AL;
    float acc = bact[a];
#pragma unroll
    for (int k = 0; k < AL; k++) acc = fmaf(lb[k], Wact[k * AA + a], acc);
    out[O_ACT + i] = acc;
  }
}

extern "C" void kernel_launch(void* const* d_in, const int* in_sizes, int n_in,
                              void* d_out, int out_size, void* d_ws, size_t ws_size,
                              hipStream_t stream) {
  const float* pos     = (const float*)d_in[0];
  const int*   batch   = (const int*)d_in[1];
  const float* agent_h = (const float*)d_in[2];
  // d_in[3], d_in[4]: coherence_*_prev — unused by the math.
  const float* Wf1  = (const float*)d_in[5];
  const float* bf1v = (const float*)d_in[6];
  const float* Wf2  = (const float*)d_in[7];
  const float* bf2v = (const float*)d_in[8];
  const float* Wg1  = (const float*)d_in[9];
  const float* bg1v = (const float*)d_in[10];
  const float* Wg2  = (const float*)d_in[11];
  const float* bg2v = (const float*)d_in[12];
  const float* Wx   = (const float*)d_in[13];
  const float* Wh   = (const float*)d_in[14];
  const float* bx   = (const float*)d_in[15];
  const float* bh   = (const float*)d_in[16];
  const float* Wlat = (const float*)d_in[17];
  const float* blat = (const float*)d_in[18];
  const float* Wact = (const float*)d_in[19];
  const float* bact = (const float*)d_in[20];
  float* out = (float*)d_out;
  float* ws = (float*)d_ws;

  // ws is re-poisoned 0xAA before every launch — zero the accumulators.
  hipMemsetAsync(ws, 0, B_SEG * 18 * sizeof(float), stream);

  point_kernel<<<1024, 256, 0, stream>>>(pos, batch, Wf1, bf1v, Wf2, bf2v,
                                         Wg1, bg1v, Wg2, bg2v, out, ws);
  agent_kernel<<<1, 256, 0, stream>>>(ws, agent_h, Wx, Wh, bx, bh,
                                      Wlat, blat, Wact, bact, out);
}

// Round 4
// 451.247 us; speedup vs baseline: 1.0678x; 1.0678x over previous
//
#include <hip/hip_runtime.h>
#include <stdint.h>

#define N_PTS 1000000
#define B_SEG 64
#define HID 128
#define AFFD 16
#define AH 64
#define AL 32
#define AA 8

// Output flat offsets in FLOAT elements (return order: affordances, recon_pos,
// coh_signal, coh_spatial, agent_action, agent_h_next). Output dtype: float32.
#define O_AFF 0
#define O_REC (16 * N_PTS)
#define O_SIG (19 * N_PTS)
#define O_SPA (19 * N_PTS + B_SEG)
#define O_ACT (20 * N_PTS + B_SEG)
#define O_HN  (20 * N_PTS + B_SEG + B_SEG * AA)

// ---------------------------------------------------------------------------
// Kernel 1: per-point MLPs (F then G), per-point outputs, segment-sum into ws.
// ws layout: [seg][18] = {err_sum, count, aff_sum[16]}   (fp32)
//
// All weight reads use wave-UNIFORM addresses (loop index j + kernel-arg
// base) from uniform control flow -> compiler emits s_load (scalar pipe,
// SGPR operands). No LDS at all: R3 profiling showed the LDS-staged version
// was LDS-issue-bound (5 ds_read_b128 = ~60 cyc vs 40 VALU cyc per j, LDS
// pipe shared by 4 SIMDs -> VALUBusy 32%).
// ---------------------------------------------------------------------------
__global__ __launch_bounds__(256, 8) void point_kernel(
    const float* __restrict__ pos, const int* __restrict__ batch,
    const float* __restrict__ Wf1, const float* __restrict__ bf1v,
    const float* __restrict__ Wf2, const float* __restrict__ bf2v,
    const float* __restrict__ Wg1, const float* __restrict__ bg1v,
    const float* __restrict__ Wg2, const float* __restrict__ bg2v,
    float* __restrict__ out, float* __restrict__ ws) {
  const int tid = threadIdx.x;
  int p = blockIdx.x * 256 + tid;
  const bool valid = (p < N_PTS);
  if (!valid) p = N_PTS - 1;  // clamp: keep hot loops in uniform control flow

  const float px = pos[p * 3 + 0];
  const float py = pos[p * 3 + 1];
  const float pz = pos[p * 3 + 2];
  const int seg = batch[p];

  float aff[AFFD];
#pragma unroll
  for (int k = 0; k < AFFD; k++) aff[k] = bf2v[k];  // uniform -> s_load

  // F: 3 -> 128 (relu) -> 16. Weights via scalar loads.
#pragma unroll 4
  for (int j = 0; j < HID; j++) {
    const float w0 = Wf1[0 * HID + j];
    const float w1 = Wf1[1 * HID + j];
    const float w2 = Wf1[2 * HID + j];
    const float b1 = bf1v[j];
    float h = fmaf(px, w0, fmaf(py, w1, fmaf(pz, w2, b1)));
    h = fmaxf(h, 0.f);
#pragma unroll
    for (int k = 0; k < AFFD; k++)
      aff[k] = fmaf(h, Wf2[j * AFFD + k], aff[k]);
  }

  // G: 16 -> 128 (relu) -> 3. Weights via scalar loads.
  float rc0 = bg2v[0], rc1 = bg2v[1], rc2 = bg2v[2];
#pragma unroll 4
  for (int j = 0; j < HID; j++) {
    float h = bg1v[j];
#pragma unroll
    for (int k = 0; k < AFFD; k++)
      h = fmaf(aff[k], Wg1[k * HID + j], h);
    h = fmaxf(h, 0.f);
    rc0 = fmaf(h, Wg2[j * 3 + 0], rc0);
    rc1 = fmaf(h, Wg2[j * 3 + 1], rc1);
    rc2 = fmaf(h, Wg2[j * 3 + 2], rc2);
  }

  const float dx = px - rc0, dy = py - rc1, dz = pz - rc2;
  const float err = fmaf(dx, dx, fmaf(dy, dy, dz * dz));

  if (valid) {
    float4* oa = (float4*)(out + O_AFF + (size_t)p * 16);  // 64B-aligned
    oa[0] = make_float4(aff[0], aff[1], aff[2], aff[3]);
    oa[1] = make_float4(aff[4], aff[5], aff[6], aff[7]);
    oa[2] = make_float4(aff[8], aff[9], aff[10], aff[11]);
    oa[3] = make_float4(aff[12], aff[13], aff[14], aff[15]);
    float* orc = out + O_REC + (size_t)p * 3;
    orc[0] = rc0;
    orc[1] = rc1;
    orc[2] = rc2;
    out[O_SPA + p] = err;
  }

  // --- segment reduction: 18 values {err, count, aff[16]} ---
  float v[18];
  v[0] = valid ? err : 0.f;
  v[1] = valid ? 1.f : 0.f;
#pragma unroll
  for (int k = 0; k < AFFD; k++) v[2 + k] = valid ? aff[k] : 0.f;

  const int first = __shfl(seg, 0);
  const bool uni = __all(seg == first);
  if (uni) {
#pragma unroll
    for (int i = 0; i < 18; i++) {
      float x = v[i];
      x += __shfl_down(x, 32);
      x += __shfl_down(x, 16);
      x += __shfl_down(x, 8);
      x += __shfl_down(x, 4);
      x += __shfl_down(x, 2);
      x += __shfl_down(x, 1);
      v[i] = x;
    }
    if ((tid & 63) == 0) {
#pragma unroll
      for (int i = 0; i < 18; i++) atomicAdd(&ws[first * 18 + i], v[i]);
    }
  } else {
#pragma unroll
    for (int i = 0; i < 18; i++) atomicAdd(&ws[seg * 18 + i], v[i]);
  }
}

// ---------------------------------------------------------------------------
// Kernel 2: one block per segment (64 blocks x 64 threads) — R3's single-block
// version serialized ~100 µs on one CU. Coalesced weight column loads.
// ---------------------------------------------------------------------------
__global__ __launch_bounds__(64) void agent_kernel(
    const float* __restrict__ ws, const float* __restrict__ agent_h,
    const float* __restrict__ Wx, const float* __restrict__ Wh,
    const float* __restrict__ bx, const float* __restrict__ bh,
    const float* __restrict__ Wlat, const float* __restrict__ blat,
    const float* __restrict__ Wact, const float* __restrict__ bact,
    float* __restrict__ out) {
  const int b = blockIdx.x;   // segment
  const int t = threadIdx.x;  // 0..63
  __shared__ float sAff[AFFD];
  __shared__ float sHn[AH];
  __shared__ float sLat[AL];

  const float cnt = fmaxf(ws[b * 18 + 1], 1.f);
  if (t == 0) out[O_SIG + b] = ws[b * 18 + 0] / cnt;
  if (t < AFFD) sAff[t] = ws[b * 18 + 2 + t] / cnt;
  const float h_prev = agent_h[b * AH + t];
  __syncthreads();

  // GRU element (b, t): column t of Wx/Wh -> coalesced across lanes.
  float pr  = bx[t] + bh[t];
  float pz  = bx[64 + t] + bh[64 + t];
  float pnx = bx[128 + t];
  float pnh = bh[128 + t];
#pragma unroll
  for (int k = 0; k < AFFD; k++) {
    const float a = sAff[k];
    pr  = fmaf(a, Wx[k * 192 + t], pr);
    pz  = fmaf(a, Wx[k * 192 + 64 + t], pz);
    pnx = fmaf(a, Wx[k * 192 + 128 + t], pnx);
  }
#pragma unroll
  for (int k = 0; k < AH; k++) {
    const float h = __shfl(h_prev, k);  // sH[k] via cross-lane, no LDS
    pr  = fmaf(h, Wh[k * 192 + t], pr);
    pz  = fmaf(h, Wh[k * 192 + 64 + t], pz);
    pnh = fmaf(h, Wh[k * 192 + 128 + t], pnh);
  }
  const float r = 1.f / (1.f + expf(-pr));
  const float z = 1.f / (1.f + expf(-pz));
  const float n = tanhf(pnx + r * pnh);
  const float hn = fmaf(1.f - z, n, z * h_prev);
  sHn[t] = hn;
  out[O_HN + b * AH + t] = hn;
  __syncthreads();

  if (t < AL) {
    float acc = blat[t];
#pragma unroll
    for (int k = 0; k < AH; k++) acc = fmaf(sHn[k], Wlat[k * AL + t], acc);
    sLat[t] = tanhf(acc);
  }
  __syncthreads();

  if (t < AA) {
    float acc = bact[t];
#pragma unroll
    for (int k = 0; k < AL; k++) acc = fmaf(sLat[k], Wact[k * AA + t], acc);
    out[O_ACT + b * AA + t] = acc;
  }
}

extern "C" void kernel_launch(void* const* d_in, const int* in_sizes, int n_in,
                              void* d_out, int out_size, void* d_ws, size_t ws_size,
                              hipStream_t stream) {
  const float* pos     = (const float*)d_in[0];
  const int*   batch   = (const int*)d_in[1];
  const float* agent_h = (const float*)d_in[2];
  // d_in[3], d_in[4]: coherence_*_prev — unused by the math.
  const float* Wf1  = (const float*)d_in[5];
  const float* bf1v = (const float*)d_in[6];
  const float* Wf2  = (const float*)d_in[7];
  const float* bf2v = (const float*)d_in[8];
  const float* Wg1  = (const float*)d_in[9];
  const float* bg1v = (const float*)d_in[10];
  const float* Wg2  = (const float*)d_in[11];
  const float* bg2v = (const float*)d_in[12];
  const float* Wx   = (const float*)d_in[13];
  const float* Wh   = (const float*)d_in[14];
  const float* bx   = (const float*)d_in[15];
  const float* bh   = (const float*)d_in[16];
  const float* Wlat = (const float*)d_in[17];
  const float* blat = (const float*)d_in[18];
  const float* Wact = (const float*)d_in[19];
  const float* bact = (const float*)d_in[20];
  float* out = (float*)d_out;
  float* ws = (float*)d_ws;

  // ws is re-poisoned 0xAA before every launch — zero the accumulators.
  hipMemsetAsync(ws, 0, B_SEG * 18 * sizeof(float), stream);

  const int nblk = (N_PTS + 255) / 256;  // 3907: one point per thread
  point_kernel<<<nblk, 256, 0, stream>>>(pos, batch, Wf1, bf1v, Wf2, bf2v,
                                         Wg1, bg1v, Wg2, bg2v, out, ws);
  agent_kernel<<<B_SEG, 64, 0, stream>>>(ws, agent_h, Wx, Wh, bx, bh,
                                         Wlat, blat, Wact, bact, out);
}

// Round 5
// 312.033 us; speedup vs baseline: 1.5443x; 1.4462x over previous
//
#include <hip/hip_runtime.h>
#include <stdint.h>

#define N_PTS 1000000
#define B_SEG 64
#define HID 128
#define AFFD 16
#define AH 64
#define AL 32
#define AA 8
#define P 8           // points per thread
#define PTS_BLK 2048  // 256 threads * P

// Output flat offsets in FLOAT elements (return order: affordances, recon_pos,
// coh_signal, coh_spatial, agent_action, agent_h_next). Output dtype: float32.
#define O_AFF 0
#define O_REC (16 * N_PTS)
#define O_SIG (19 * N_PTS)
#define O_SPA (19 * N_PTS + B_SEG)
#define O_ACT (20 * N_PTS + B_SEG)
#define O_HN  (20 * N_PTS + B_SEG + B_SEG * AA)

// ---------------------------------------------------------------------------
// Kernel 1: per-point MLPs, P=8 points/thread so each broadcast LDS weight
// read feeds 8x the FMAs (R3: 1:1 fetch:FMA -> LDS-bound 32% VALU; R4:
// per-lane VMEM weight loads -> latency-bound 33% VALU).
// ws layout: [seg][18] = {err_sum, count, aff_sum[16]}   (fp32)
// ---------------------------------------------------------------------------
__global__ __launch_bounds__(256, 2) void point_kernel(
    const float* __restrict__ pos, const int* __restrict__ batch,
    const float* __restrict__ Wf1, const float* __restrict__ bf1v,
    const float* __restrict__ Wf2, const float* __restrict__ bf2v,
    const float* __restrict__ Wg1, const float* __restrict__ bg1v,
    const float* __restrict__ Wg2, const float* __restrict__ bg2v,
    float* __restrict__ out, float* __restrict__ ws) {
  __shared__ float sF1[HID * 4];    // j*4: Wf1[0][j], Wf1[1][j], Wf1[2][j], bf1[j]
  __shared__ float sF2[HID * AFFD]; // j*16+k : Wf2[j][k]
  __shared__ float sG1[HID * AFFD]; // j*16+k : Wg1[k][j]  (transposed)
  __shared__ float sG2[HID * 4];    // j*4: Wg2[j][0..2], bg1[j]
  __shared__ float sBf2[AFFD];

  const int tid = threadIdx.x;
  for (int j = tid; j < HID; j += 256) {
    sF1[j * 4 + 0] = Wf1[0 * HID + j];
    sF1[j * 4 + 1] = Wf1[1 * HID + j];
    sF1[j * 4 + 2] = Wf1[2 * HID + j];
    sF1[j * 4 + 3] = bf1v[j];
    sG2[j * 4 + 0] = Wg2[j * 3 + 0];
    sG2[j * 4 + 1] = Wg2[j * 3 + 1];
    sG2[j * 4 + 2] = Wg2[j * 3 + 2];
    sG2[j * 4 + 3] = bg1v[j];
  }
  for (int i = tid; i < HID * AFFD; i += 256) {
    sF2[i] = Wf2[i];
    int j = i >> 4, k = i & 15;
    sG1[i] = Wg1[k * HID + j];
  }
  if (tid < AFFD) sBf2[tid] = bf2v[tid];
  const float bg20 = bg2v[0], bg21 = bg2v[1], bg22 = bg2v[2];
  __syncthreads();

  const float4* sF1v = (const float4*)sF1;
  const float4* sG2v = (const float4*)sG2;
  const float4* sF2v = (const float4*)sF2;
  const float4* sG1v = (const float4*)sG1;

  const int base = blockIdx.x * PTS_BLK;

  float px[P], py[P], pz[P];
  int seg[P];
  bool val[P];
#pragma unroll
  for (int i = 0; i < P; i++) {
    int p = base + i * 256 + tid;
    val[i] = (p < N_PTS);
    if (!val[i]) p = N_PTS - 1;  // clamp: uniform control flow in hot loops
    px[i] = pos[p * 3 + 0];
    py[i] = pos[p * 3 + 1];
    pz[i] = pos[p * 3 + 2];
    seg[i] = batch[p];
  }

  float aff[P][AFFD];
#pragma unroll
  for (int i = 0; i < P; i++)
#pragma unroll
    for (int k = 0; k < AFFD; k++) aff[i][k] = sBf2[k];

  // F: 3 -> 128 (relu) -> 16.  5 broadcast LDS reads feed 160 FMAs.
#pragma unroll 2
  for (int j = 0; j < HID; j++) {
    const float4 w = sF1v[j];
    const float4 r0 = sF2v[j * 4 + 0];
    const float4 r1 = sF2v[j * 4 + 1];
    const float4 r2 = sF2v[j * 4 + 2];
    const float4 r3 = sF2v[j * 4 + 3];
#pragma unroll
    for (int i = 0; i < P; i++) {
      float h = fmaf(px[i], w.x, fmaf(py[i], w.y, fmaf(pz[i], w.z, w.w)));
      h = fmaxf(h, 0.f);
      aff[i][0]  = fmaf(h, r0.x, aff[i][0]);  aff[i][1]  = fmaf(h, r0.y, aff[i][1]);
      aff[i][2]  = fmaf(h, r0.z, aff[i][2]);  aff[i][3]  = fmaf(h, r0.w, aff[i][3]);
      aff[i][4]  = fmaf(h, r1.x, aff[i][4]);  aff[i][5]  = fmaf(h, r1.y, aff[i][5]);
      aff[i][6]  = fmaf(h, r1.z, aff[i][6]);  aff[i][7]  = fmaf(h, r1.w, aff[i][7]);
      aff[i][8]  = fmaf(h, r2.x, aff[i][8]);  aff[i][9]  = fmaf(h, r2.y, aff[i][9]);
      aff[i][10] = fmaf(h, r2.z, aff[i][10]); aff[i][11] = fmaf(h, r2.w, aff[i][11]);
      aff[i][12] = fmaf(h, r3.x, aff[i][12]); aff[i][13] = fmaf(h, r3.y, aff[i][13]);
      aff[i][14] = fmaf(h, r3.z, aff[i][14]); aff[i][15] = fmaf(h, r3.w, aff[i][15]);
    }
  }

  // G: 16 -> 128 (relu) -> 3.
  float rc0[P], rc1[P], rc2[P];
#pragma unroll
  for (int i = 0; i < P; i++) { rc0[i] = bg20; rc1[i] = bg21; rc2[i] = bg22; }
#pragma unroll 2
  for (int j = 0; j < HID; j++) {
    const float4 g = sG2v[j];
    const float4 r0 = sG1v[j * 4 + 0];
    const float4 r1 = sG1v[j * 4 + 1];
    const float4 r2 = sG1v[j * 4 + 2];
    const float4 r3 = sG1v[j * 4 + 3];
#pragma unroll
    for (int i = 0; i < P; i++) {
      float h = g.w;
      h = fmaf(aff[i][0], r0.x, h);  h = fmaf(aff[i][1], r0.y, h);
      h = fmaf(aff[i][2], r0.z, h);  h = fmaf(aff[i][3], r0.w, h);
      h = fmaf(aff[i][4], r1.x, h);  h = fmaf(aff[i][5], r1.y, h);
      h = fmaf(aff[i][6], r1.z, h);  h = fmaf(aff[i][7], r1.w, h);
      h = fmaf(aff[i][8], r2.x, h);  h = fmaf(aff[i][9], r2.y, h);
      h = fmaf(aff[i][10], r2.z, h); h = fmaf(aff[i][11], r2.w, h);
      h = fmaf(aff[i][12], r3.x, h); h = fmaf(aff[i][13], r3.y, h);
      h = fmaf(aff[i][14], r3.z, h); h = fmaf(aff[i][15], r3.w, h);
      h = fmaxf(h, 0.f);
      rc0[i] = fmaf(h, g.x, rc0[i]);
      rc1[i] = fmaf(h, g.y, rc1[i]);
      rc2[i] = fmaf(h, g.z, rc2[i]);
    }
  }

  // Errors + stores.
  float err[P];
#pragma unroll
  for (int i = 0; i < P; i++) {
    const float dx = px[i] - rc0[i], dy = py[i] - rc1[i], dz = pz[i] - rc2[i];
    err[i] = fmaf(dx, dx, fmaf(dy, dy, dz * dz));
    if (val[i]) {
      const int p = base + i * 256 + tid;
      float4* oa = (float4*)(out + O_AFF + (size_t)p * 16);
      oa[0] = make_float4(aff[i][0], aff[i][1], aff[i][2], aff[i][3]);
      oa[1] = make_float4(aff[i][4], aff[i][5], aff[i][6], aff[i][7]);
      oa[2] = make_float4(aff[i][8], aff[i][9], aff[i][10], aff[i][11]);
      oa[3] = make_float4(aff[i][12], aff[i][13], aff[i][14], aff[i][15]);
      float* orc = out + O_REC + (size_t)p * 3;
      orc[0] = rc0[i]; orc[1] = rc1[i]; orc[2] = rc2[i];
      out[O_SPA + p] = err[i];
    }
  }

  // --- segment reduction ---
  // Fast path: this thread's 8 points all valid & same seg, and seg is
  // wave-uniform (true for ~97% of waves: segments average ~15.6k points).
  bool tok = val[0] && val[P - 1];
#pragma unroll
  for (int i = 1; i < P; i++) tok = tok && (seg[i] == seg[0]) && val[i];
  const int wseg = __shfl(seg[0], 0);
  const bool fast = __all(tok && (seg[0] == wseg));

  if (fast) {
    float v[18];
    v[0] = 0.f;
#pragma unroll
    for (int i = 0; i < P; i++) v[0] += err[i];
    v[1] = (float)P;
#pragma unroll
    for (int k = 0; k < AFFD; k++) {
      float s = 0.f;
#pragma unroll
      for (int i = 0; i < P; i++) s += aff[i][k];
      v[2 + k] = s;
    }
#pragma unroll
    for (int i = 0; i < 18; i++) {
      float x = v[i];
      x += __shfl_down(x, 32);
      x += __shfl_down(x, 16);
      x += __shfl_down(x, 8);
      x += __shfl_down(x, 4);
      x += __shfl_down(x, 2);
      x += __shfl_down(x, 1);
      v[i] = x;
    }
    if ((tid & 63) == 0) {
#pragma unroll
      for (int i = 0; i < 18; i++) atomicAdd(&ws[wseg * 18 + i], v[i]);
    }
  } else {
    // Slow path: handle each i-slice (64 consecutive points per wave).
#pragma unroll
    for (int i = 0; i < P; i++) {
      float v[18];
      v[0] = val[i] ? err[i] : 0.f;
      v[1] = val[i] ? 1.f : 0.f;
#pragma unroll
      for (int k = 0; k < AFFD; k++) v[2 + k] = val[i] ? aff[i][k] : 0.f;
      const int fi = __shfl(seg[i], 0);
      const bool uni = __all((seg[i] == fi) || !val[i]);
      if (uni) {
#pragma unroll
        for (int q = 0; q < 18; q++) {
          float x = v[q];
          x += __shfl_down(x, 32);
          x += __shfl_down(x, 16);
          x += __shfl_down(x, 8);
          x += __shfl_down(x, 4);
          x += __shfl_down(x, 2);
          x += __shfl_down(x, 1);
          v[q] = x;
        }
        if ((tid & 63) == 0) {
#pragma unroll
          for (int q = 0; q < 18; q++) atomicAdd(&ws[fi * 18 + q], v[q]);
        }
      } else if (val[i]) {
#pragma unroll
        for (int q = 0; q < 18; q++) atomicAdd(&ws[seg[i] * 18 + q], v[q]);
      }
    }
  }
}

// ---------------------------------------------------------------------------
// Kernel 2: one block per segment (64 blocks x 64 threads).
// ---------------------------------------------------------------------------
__global__ __launch_bounds__(64) void agent_kernel(
    const float* __restrict__ ws, const float* __restrict__ agent_h,
    const float* __restrict__ Wx, const float* __restrict__ Wh,
    const float* __restrict__ bx, const float* __restrict__ bh,
    const float* __restrict__ Wlat, const float* __restrict__ blat,
    const float* __restrict__ Wact, const float* __restrict__ bact,
    float* __restrict__ out) {
  const int b = blockIdx.x;   // segment
  const int t = threadIdx.x;  // 0..63
  __shared__ float sAff[AFFD];
  __shared__ float sHn[AH];
  __shared__ float sLat[AL];

  const float cnt = fmaxf(ws[b * 18 + 1], 1.f);
  if (t == 0) out[O_SIG + b] = ws[b * 18 + 0] / cnt;
  if (t < AFFD) sAff[t] = ws[b * 18 + 2 + t] / cnt;
  const float h_prev = agent_h[b * AH + t];
  __syncthreads();

  float pr  = bx[t] + bh[t];
  float pz  = bx[64 + t] + bh[64 + t];
  float pnx = bx[128 + t];
  float pnh = bh[128 + t];
#pragma unroll
  for (int k = 0; k < AFFD; k++) {
    const float a = sAff[k];
    pr  = fmaf(a, Wx[k * 192 + t], pr);
    pz  = fmaf(a, Wx[k * 192 + 64 + t], pz);
    pnx = fmaf(a, Wx[k * 192 + 128 + t], pnx);
  }
#pragma unroll
  for (int k = 0; k < AH; k++) {
    const float h = __shfl(h_prev, k);
    pr  = fmaf(h, Wh[k * 192 + t], pr);
    pz  = fmaf(h, Wh[k * 192 + 64 + t], pz);
    pnh = fmaf(h, Wh[k * 192 + 128 + t], pnh);
  }
  const float r = 1.f / (1.f + expf(-pr));
  const float z = 1.f / (1.f + expf(-pz));
  const float n = tanhf(pnx + r * pnh);
  const float hn = fmaf(1.f - z, n, z * h_prev);
  sHn[t] = hn;
  out[O_HN + b * AH + t] = hn;
  __syncthreads();

  if (t < AL) {
    float acc = blat[t];
#pragma unroll
    for (int k = 0; k < AH; k++) acc = fmaf(sHn[k], Wlat[k * AL + t], acc);
    sLat[t] = tanhf(acc);
  }
  __syncthreads();

  if (t < AA) {
    float acc = bact[t];
#pragma unroll
    for (int k = 0; k < AL; k++) acc = fmaf(sLat[k], Wact[k * AA + t], acc);
    out[O_ACT + b * AA + t] = acc;
  }
}

extern "C" void kernel_launch(void* const* d_in, const int* in_sizes, int n_in,
                              void* d_out, int out_size, void* d_ws, size_t ws_size,
                              hipStream_t stream) {
  const float* pos     = (const float*)d_in[0];
  const int*   batch   = (const int*)d_in[1];
  const float* agent_h = (const float*)d_in[2];
  // d_in[3], d_in[4]: coherence_*_prev — unused by the math.
  const float* Wf1  = (const float*)d_in[5];
  const float* bf1v = (const float*)d_in[6];
  const float* Wf2  = (const float*)d_in[7];
  const float* bf2v = (const float*)d_in[8];
  const float* Wg1  = (const float*)d_in[9];
  const float* bg1v = (const float*)d_in[10];
  const float* Wg2  = (const float*)d_in[11];
  const float* bg2v = (const float*)d_in[12];
  const float* Wx   = (const float*)d_in[13];
  const float* Wh   = (const float*)d_in[14];
  const float* bx   = (const float*)d_in[15];
  const float* bh   = (const float*)d_in[16];
  const float* Wlat = (const float*)d_in[17];
  const float* blat = (const float*)d_in[18];
  const float* Wact = (const float*)d_in[19];
  const float* bact = (const float*)d_in[20];
  float* out = (float*)d_out;
  float* ws = (float*)d_ws;

  // ws is re-poisoned 0xAA before every launch — zero the accumulators.
  hipMemsetAsync(ws, 0, B_SEG * 18 * sizeof(float), stream);

  const int nblk = (N_PTS + PTS_BLK - 1) / PTS_BLK;  // 489
  point_kernel<<<nblk, 256, 0, stream>>>(pos, batch, Wf1, bf1v, Wf2, bf2v,
                                         Wg1, bg1v, Wg2, bg2v, out, ws);
  agent_kernel<<<B_SEG, 64, 0, stream>>>(ws, agent_h, Wx, Wh, bx, bh,
                                         Wlat, blat, Wact, bact, out);
}

// Round 6
// 307.616 us; speedup vs baseline: 1.5664x; 1.0144x over previous
//
#include <hip/hip_runtime.h>
#include <stdint.h>

#define N_PTS 1000000
#define B_SEG 64
#define HID 128
#define AFFD 16
#define AH 64
#define AL 32
#define AA 8
#define TPB 128       // threads per block (2 waves)
#define P 8           // points per thread
#define PTS_BLK (TPB * P)  // 1024

// Output flat offsets in FLOAT elements (return order: affordances, recon_pos,
// coh_signal, coh_spatial, agent_action, agent_h_next). Output dtype: float32.
#define O_AFF 0
#define O_REC (16 * N_PTS)
#define O_SIG (19 * N_PTS)
#define O_SPA (19 * N_PTS + B_SEG)
#define O_ACT (20 * N_PTS + B_SEG)
#define O_HN  (20 * N_PTS + B_SEG + B_SEG * AA)

// ---------------------------------------------------------------------------
// Kernel 1: per-point MLPs, P=8 points/thread (LDS broadcast weights feed
// 8x FMAs). R5 lesson: 256-thread blocks + launch_bounds(256,2) made the
// compiler pick 128 VGPR and spill the ~180-reg working set to scratch
// (VALUBusy 54%, 70k vs 46k instrs/wave), and 489 blocks under-filled the
// 256 CUs (occupancy 13.8%). 128-thread blocks + (128,2) -> 256-VGPR budget
// (no spill) and 977 blocks (even CU fill).
// ws layout: [seg][18] = {err_sum, count, aff_sum[16]}   (fp32)
// ---------------------------------------------------------------------------
__global__ __launch_bounds__(TPB, 2) void point_kernel(
    const float* __restrict__ pos, const int* __restrict__ batch,
    const float* __restrict__ Wf1, const float* __restrict__ bf1v,
    const float* __restrict__ Wf2, const float* __restrict__ bf2v,
    const float* __restrict__ Wg1, const float* __restrict__ bg1v,
    const float* __restrict__ Wg2, const float* __restrict__ bg2v,
    float* __restrict__ out, float* __restrict__ ws) {
  __shared__ float sF1[HID * 4];    // j*4: Wf1[0][j], Wf1[1][j], Wf1[2][j], bf1[j]
  __shared__ float sF2[HID * AFFD]; // j*16+k : Wf2[j][k]
  __shared__ float sG1[HID * AFFD]; // j*16+k : Wg1[k][j]  (transposed)
  __shared__ float sG2[HID * 4];    // j*4: Wg2[j][0..2], bg1[j]
  __shared__ float sBf2[AFFD];

  const int tid = threadIdx.x;
  for (int j = tid; j < HID; j += TPB) {
    sF1[j * 4 + 0] = Wf1[0 * HID + j];
    sF1[j * 4 + 1] = Wf1[1 * HID + j];
    sF1[j * 4 + 2] = Wf1[2 * HID + j];
    sF1[j * 4 + 3] = bf1v[j];
    sG2[j * 4 + 0] = Wg2[j * 3 + 0];
    sG2[j * 4 + 1] = Wg2[j * 3 + 1];
    sG2[j * 4 + 2] = Wg2[j * 3 + 2];
    sG2[j * 4 + 3] = bg1v[j];
  }
  for (int i = tid; i < HID * AFFD; i += TPB) {
    sF2[i] = Wf2[i];
    int j = i >> 4, k = i & 15;
    sG1[i] = Wg1[k * HID + j];
  }
  if (tid < AFFD) sBf2[tid] = bf2v[tid];
  const float bg20 = bg2v[0], bg21 = bg2v[1], bg22 = bg2v[2];
  __syncthreads();

  const float4* sF1v = (const float4*)sF1;
  const float4* sG2v = (const float4*)sG2;
  const float4* sF2v = (const float4*)sF2;
  const float4* sG1v = (const float4*)sG1;

  const int base = blockIdx.x * PTS_BLK;

  float px[P], py[P], pz[P];
  int seg[P];
  bool val[P];
#pragma unroll
  for (int i = 0; i < P; i++) {
    int p = base + i * TPB + tid;
    val[i] = (p < N_PTS);
    if (!val[i]) p = N_PTS - 1;  // clamp: uniform control flow in hot loops
    px[i] = pos[p * 3 + 0];
    py[i] = pos[p * 3 + 1];
    pz[i] = pos[p * 3 + 2];
    seg[i] = batch[p];
  }

  float aff[P][AFFD];
#pragma unroll
  for (int i = 0; i < P; i++)
#pragma unroll
    for (int k = 0; k < AFFD; k++) aff[i][k] = sBf2[k];

  // F: 3 -> 128 (relu) -> 16.  5 broadcast LDS reads feed 160 FMAs.
#pragma unroll 2
  for (int j = 0; j < HID; j++) {
    const float4 w = sF1v[j];
    const float4 r0 = sF2v[j * 4 + 0];
    const float4 r1 = sF2v[j * 4 + 1];
    const float4 r2 = sF2v[j * 4 + 2];
    const float4 r3 = sF2v[j * 4 + 3];
#pragma unroll
    for (int i = 0; i < P; i++) {
      float h = fmaf(px[i], w.x, fmaf(py[i], w.y, fmaf(pz[i], w.z, w.w)));
      h = fmaxf(h, 0.f);
      aff[i][0]  = fmaf(h, r0.x, aff[i][0]);  aff[i][1]  = fmaf(h, r0.y, aff[i][1]);
      aff[i][2]  = fmaf(h, r0.z, aff[i][2]);  aff[i][3]  = fmaf(h, r0.w, aff[i][3]);
      aff[i][4]  = fmaf(h, r1.x, aff[i][4]);  aff[i][5]  = fmaf(h, r1.y, aff[i][5]);
      aff[i][6]  = fmaf(h, r1.z, aff[i][6]);  aff[i][7]  = fmaf(h, r1.w, aff[i][7]);
      aff[i][8]  = fmaf(h, r2.x, aff[i][8]);  aff[i][9]  = fmaf(h, r2.y, aff[i][9]);
      aff[i][10] = fmaf(h, r2.z, aff[i][10]); aff[i][11] = fmaf(h, r2.w, aff[i][11]);
      aff[i][12] = fmaf(h, r3.x, aff[i][12]); aff[i][13] = fmaf(h, r3.y, aff[i][13]);
      aff[i][14] = fmaf(h, r3.z, aff[i][14]); aff[i][15] = fmaf(h, r3.w, aff[i][15]);
    }
  }

  // G: 16 -> 128 (relu) -> 3.
  float rc0[P], rc1[P], rc2[P];
#pragma unroll
  for (int i = 0; i < P; i++) { rc0[i] = bg20; rc1[i] = bg21; rc2[i] = bg22; }
#pragma unroll 2
  for (int j = 0; j < HID; j++) {
    const float4 g = sG2v[j];
    const float4 r0 = sG1v[j * 4 + 0];
    const float4 r1 = sG1v[j * 4 + 1];
    const float4 r2 = sG1v[j * 4 + 2];
    const float4 r3 = sG1v[j * 4 + 3];
#pragma unroll
    for (int i = 0; i < P; i++) {
      float h = g.w;
      h = fmaf(aff[i][0], r0.x, h);  h = fmaf(aff[i][1], r0.y, h);
      h = fmaf(aff[i][2], r0.z, h);  h = fmaf(aff[i][3], r0.w, h);
      h = fmaf(aff[i][4], r1.x, h);  h = fmaf(aff[i][5], r1.y, h);
      h = fmaf(aff[i][6], r1.z, h);  h = fmaf(aff[i][7], r1.w, h);
      h = fmaf(aff[i][8], r2.x, h);  h = fmaf(aff[i][9], r2.y, h);
      h = fmaf(aff[i][10], r2.z, h); h = fmaf(aff[i][11], r2.w, h);
      h = fmaf(aff[i][12], r3.x, h); h = fmaf(aff[i][13], r3.y, h);
      h = fmaf(aff[i][14], r3.z, h); h = fmaf(aff[i][15], r3.w, h);
      h = fmaxf(h, 0.f);
      rc0[i] = fmaf(h, g.x, rc0[i]);
      rc1[i] = fmaf(h, g.y, rc1[i]);
      rc2[i] = fmaf(h, g.z, rc2[i]);
    }
  }

  // Errors + stores.
  float err[P];
#pragma unroll
  for (int i = 0; i < P; i++) {
    const float dx = px[i] - rc0[i], dy = py[i] - rc1[i], dz = pz[i] - rc2[i];
    err[i] = fmaf(dx, dx, fmaf(dy, dy, dz * dz));
    if (val[i]) {
      const int p = base + i * TPB + tid;
      float4* oa = (float4*)(out + O_AFF + (size_t)p * 16);
      oa[0] = make_float4(aff[i][0], aff[i][1], aff[i][2], aff[i][3]);
      oa[1] = make_float4(aff[i][4], aff[i][5], aff[i][6], aff[i][7]);
      oa[2] = make_float4(aff[i][8], aff[i][9], aff[i][10], aff[i][11]);
      oa[3] = make_float4(aff[i][12], aff[i][13], aff[i][14], aff[i][15]);
      float* orc = out + O_REC + (size_t)p * 3;
      orc[0] = rc0[i]; orc[1] = rc1[i]; orc[2] = rc2[i];
      out[O_SPA + p] = err[i];
    }
  }

  // --- segment reduction ---
  // Fast path: this thread's 8 points all valid & same seg, and seg is
  // wave-uniform (true for nearly all waves: segments average ~15.6k points).
  bool tok = true;
#pragma unroll
  for (int i = 0; i < P; i++) tok = tok && (seg[i] == seg[0]) && val[i];
  const int wseg = __shfl(seg[0], 0);
  const bool fast = __all(tok && (seg[0] == wseg));

  if (fast) {
    float v[18];
    v[0] = 0.f;
#pragma unroll
    for (int i = 0; i < P; i++) v[0] += err[i];
    v[1] = (float)P;
#pragma unroll
    for (int k = 0; k < AFFD; k++) {
      float s = 0.f;
#pragma unroll
      for (int i = 0; i < P; i++) s += aff[i][k];
      v[2 + k] = s;
    }
#pragma unroll
    for (int i = 0; i < 18; i++) {
      float x = v[i];
      x += __shfl_down(x, 32);
      x += __shfl_down(x, 16);
      x += __shfl_down(x, 8);
      x += __shfl_down(x, 4);
      x += __shfl_down(x, 2);
      x += __shfl_down(x, 1);
      v[i] = x;
    }
    if ((tid & 63) == 0) {
#pragma unroll
      for (int i = 0; i < 18; i++) atomicAdd(&ws[wseg * 18 + i], v[i]);
    }
  } else {
    // Slow path: handle each i-slice (64 consecutive points per wave).
#pragma unroll
    for (int i = 0; i < P; i++) {
      float v[18];
      v[0] = val[i] ? err[i] : 0.f;
      v[1] = val[i] ? 1.f : 0.f;
#pragma unroll
      for (int k = 0; k < AFFD; k++) v[2 + k] = val[i] ? aff[i][k] : 0.f;
      const int fi = __shfl(seg[i], 0);
      const bool uni = __all((seg[i] == fi) || !val[i]);
      if (uni) {
#pragma unroll
        for (int q = 0; q < 18; q++) {
          float x = v[q];
          x += __shfl_down(x, 32);
          x += __shfl_down(x, 16);
          x += __shfl_down(x, 8);
          x += __shfl_down(x, 4);
          x += __shfl_down(x, 2);
          x += __shfl_down(x, 1);
          v[q] = x;
        }
        if ((tid & 63) == 0) {
#pragma unroll
          for (int q = 0; q < 18; q++) atomicAdd(&ws[fi * 18 + q], v[q]);
        }
      } else if (val[i]) {
#pragma unroll
        for (int q = 0; q < 18; q++) atomicAdd(&ws[seg[i] * 18 + q], v[q]);
      }
    }
  }
}

// ---------------------------------------------------------------------------
// Kernel 2: one block per segment (64 blocks x 64 threads).
// ---------------------------------------------------------------------------
__global__ __launch_bounds__(64) void agent_kernel(
    const float* __restrict__ ws, const float* __restrict__ agent_h,
    const float* __restrict__ Wx, const float* __restrict__ Wh,
    const float* __restrict__ bx, const float* __restrict__ bh,
    const float* __restrict__ Wlat, const float* __restrict__ blat,
    const float* __restrict__ Wact, const float* __restrict__ bact,
    float* __restrict__ out) {
  const int b = blockIdx.x;   // segment
  const int t = threadIdx.x;  // 0..63
  __shared__ float sAff[AFFD];
  __shared__ float sHn[AH];
  __shared__ float sLat[AL];

  const float cnt = fmaxf(ws[b * 18 + 1], 1.f);
  if (t == 0) out[O_SIG + b] = ws[b * 18 + 0] / cnt;
  if (t < AFFD) sAff[t] = ws[b * 18 + 2 + t] / cnt;
  const float h_prev = agent_h[b * AH + t];
  __syncthreads();

  float pr  = bx[t] + bh[t];
  float pz  = bx[64 + t] + bh[64 + t];
  float pnx = bx[128 + t];
  float pnh = bh[128 + t];
#pragma unroll
  for (int k = 0; k < AFFD; k++) {
    const float a = sAff[k];
    pr  = fmaf(a, Wx[k * 192 + t], pr);
    pz  = fmaf(a, Wx[k * 192 + 64 + t], pz);
    pnx = fmaf(a, Wx[k * 192 + 128 + t], pnx);
  }
#pragma unroll
  for (int k = 0; k < AH; k++) {
    const float h = __shfl(h_prev, k);
    pr  = fmaf(h, Wh[k * 192 + t], pr);
    pz  = fmaf(h, Wh[k * 192 + 64 + t], pz);
    pnh = fmaf(h, Wh[k * 192 + 128 + t], pnh);
  }
  const float r = 1.f / (1.f + expf(-pr));
  const float z = 1.f / (1.f + expf(-pz));
  const float n = tanhf(pnx + r * pnh);
  const float hn = fmaf(1.f - z, n, z * h_prev);
  sHn[t] = hn;
  out[O_HN + b * AH + t] = hn;
  __syncthreads();

  if (t < AL) {
    float acc = blat[t];
#pragma unroll
    for (int k = 0; k < AH; k++) acc = fmaf(sHn[k], Wlat[k * AL + t], acc);
    sLat[t] = tanhf(acc);
  }
  __syncthreads();

  if (t < AA) {
    float acc = bact[t];
#pragma unroll
    for (int k = 0; k < AL; k++) acc = fmaf(sLat[k], Wact[k * AA + t], acc);
    out[O_ACT + b * AA + t] = acc;
  }
}

extern "C" void kernel_launch(void* const* d_in, const int* in_sizes, int n_in,
                              void* d_out, int out_size, void* d_ws, size_t ws_size,
                              hipStream_t stream) {
  const float* pos     = (const float*)d_in[0];
  const int*   batch   = (const int*)d_in[1];
  const float* agent_h = (const float*)d_in[2];
  // d_in[3], d_in[4]: coherence_*_prev — unused by the math.
  const float* Wf1  = (const float*)d_in[5];
  const float* bf1v = (const float*)d_in[6];
  const float* Wf2  = (const float*)d_in[7];
  const float* bf2v = (const float*)d_in[8];
  const float* Wg1  = (const float*)d_in[9];
  const float* bg1v = (const float*)d_in[10];
  const float* Wg2  = (const float*)d_in[11];
  const float* bg2v = (const float*)d_in[12];
  const float* Wx   = (const float*)d_in[13];
  const float* Wh   = (const float*)d_in[14];
  const float* bx   = (const float*)d_in[15];
  const float* bh   = (const float*)d_in[16];
  const float* Wlat = (const float*)d_in[17];
  const float* blat = (const float*)d_in[18];
  const float* Wact = (const float*)d_in[19];
  const float* bact = (const float*)d_in[20];
  float* out = (float*)d_out;
  float* ws = (float*)d_ws;

  // ws is re-poisoned 0xAA before every launch — zero the accumulators.
  hipMemsetAsync(ws, 0, B_SEG * 18 * sizeof(float), stream);

  const int nblk = (N_PTS + PTS_BLK - 1) / PTS_BLK;  // 977
  point_kernel<<<nblk, TPB, 0, stream>>>(pos, batch, Wf1, bf1v, Wf2, bf2v,
                                         Wg1, bg1v, Wg2, bg2v, out, ws);
  agent_kernel<<<B_SEG, 64, 0, stream>>>(ws, agent_h, Wx, Wh, bx, bh,
                                         Wlat, blat, Wact, bact, out);
}